// Round 8
// baseline (585.301 us; speedup 1.0000x reference)
//
#include <hip/hip_runtime.h>
#include <math.h>

#define HH 512
#define WW 512
#define NB 8
#define NC 3
#define HW (HH*WW)

#define RSTRIP 8                          // output rows per wave
#define CSTRIP 62                         // output cols per wave
#define NROWS (HH/RSTRIP)                 // 64
#define NCOLS ((WW + CSTRIP - 1)/CSTRIP)  // 9
#define WPB 4                             // waves per block

// K1: register row-streaming separable conv; one 64-lane wave per 62x8 strip,
// 4 independent waves/block. Double-buffered row loads (next row's 27 f32 taps
// issued before current row's f64 compute -> latency hidden). Interior waves
// (csafe) use base+offset loads; edge waves clamp+mask (value-masked, proven).
// f64 H/V blur + sobel; GM stored f32 (decisions remain f64-accurate to 6e-8).
__global__ __launch_bounds__(256, 4) void canny_gm_kernel(
    const float* __restrict__ img, const float* __restrict__ gwin,
    float* __restrict__ GM, unsigned char* __restrict__ KP)
{
    const int lane = threadIdx.x & 63;
    const int wv   = threadIdx.x >> 6;         // 0..3
    const int cs   = blockIdx.x % NCOLS;
    const int rs   = (blockIdx.x / NCOLS) * WPB + wv;
    const int b    = blockIdx.y;

    const int R0 = rs * RSTRIP;
    const int cl = cs * CSTRIP - 1 + lane;     // this lane's blur column

    double g[9];
#pragma unroll
    for (int k = 0; k < 9; ++k) g[k] = (double)gwin[k];

    const bool csafe = (cs >= 1) && (cs <= NCOLS - 2);   // window cl-4..cl+4 in-image
    const bool lane_out = (lane >= 1) && (lane <= CSTRIP) && (cl < WW);
    const bool cml = ((unsigned)(cl - 1) < (unsigned)WW);
    const bool cmr = ((unsigned)(cl + 1) < (unsigned)WW);

    const float* ip0 = img + ((size_t)b * NC + 0) * HW;
    const float* ip1 = img + ((size_t)b * NC + 1) * HW;
    const float* ip2 = img + ((size_t)b * NC + 2) * HW;

    double hb[3][9];   // h-blur ring: row R0-5+ph -> slot ph%9
    double vr[3][3];   // v-blur ring: row R0-9+ph -> slot ph%3
#pragma unroll
    for (int c = 0; c < 3; ++c) {
#pragma unroll
        for (int k = 0; k < 9; ++k) hb[c][k] = 0.0;
#pragma unroll
        for (int k = 0; k < 3; ++k) vr[c][k] = 0.0;
    }

    const double t225 = 0.41421356237309503;   // tan(22.5 deg)
    const double t675 = 2.414213562373095;     // tan(67.5 deg)

    auto LOADROW = [&](int r, float (*v)[9]) {
        if ((unsigned)r < (unsigned)HH) {
            const size_t ro = (size_t)r * WW;
            if (csafe) {
                const float* rp0 = ip0 + ro + (cl - 4);
                const float* rp1 = ip1 + ro + (cl - 4);
                const float* rp2 = ip2 + ro + (cl - 4);
#pragma unroll
                for (int k = 0; k < 9; ++k) {
                    v[0][k] = rp0[k]; v[1][k] = rp1[k]; v[2][k] = rp2[k];
                }
            } else {
#pragma unroll
                for (int k = 0; k < 9; ++k) {
                    int cc = cl - 4 + k;
                    bool m = ((unsigned)cc < (unsigned)WW);
                    int ci = cc < 0 ? 0 : (cc > WW - 1 ? WW - 1 : cc);
                    v[0][k] = m ? ip0[ro + ci] : 0.0f;
                    v[1][k] = m ? ip1[ro + ci] : 0.0f;
                    v[2][k] = m ? ip2[ro + ci] : 0.0f;
                }
            }
        } else {
#pragma unroll
            for (int k = 0; k < 9; ++k) {
                v[0][k] = 0.0f; v[1][k] = 0.0f; v[2][k] = 0.0f;
            }
        }
    };

    auto COMPUTE = [&](int ph, const float (*v)[9]) {
        // ---- H: row r = R0-5+ph -> hb slot ph%9
#pragma unroll
        for (int c = 0; c < 3; ++c) {
            double a = 0.0;
#pragma unroll
            for (int k = 0; k < 9; ++k) a = fma(g[k], (double)v[c][k], a);
            hb[c][ph % 9] = a;
        }
        // ---- V: row rv = R0-9+ph -> vr slot ph%3; tap row R0-13+ph+k at slot (ph+1+k)%9
        if (ph >= 8) {
#pragma unroll
            for (int c = 0; c < 3; ++c) {
                double acc = 0.0;
#pragma unroll
                for (int k = 0; k < 9; ++k)
                    acc = fma(g[k], hb[c][(ph + 1 + k) % 9], acc);
                vr[c][ph % 3] = acc;
            }
        }
        // ---- S: row ri = R0-10+ph; rows ri-1,ri,ri+1 at slots (ph-2,ph-1,ph)%3
        if (ph >= 10) {
            const int ri = R0 - 10 + ph;
            const bool up = (ri >= 1), dn = (ri <= HH - 2);
            double mag = 0.0, sgx = 0.0, sgy = 0.0;
#pragma unroll
            for (int c = 0; c < 3; ++c) {
                double top = up ? vr[c][(ph - 2) % 3] : 0.0;
                double mid =      vr[c][(ph - 1) % 3];
                double bot = dn ? vr[c][ph % 3]       : 0.0;
                double s = top + 2.0 * mid + bot;   // [1,2,1] column sum
                double d = top - bot;               // vertical diff
                double sL = __shfl_up(s, 1), sR = __shfl_down(s, 1);
                double dL = __shfl_up(d, 1), dR = __shfl_down(d, 1);
                sL = cml ? sL : 0.0;  sR = cmr ? sR : 0.0;
                dL = cml ? dL : 0.0;  dR = cmr ? dR : 0.0;
                double gx = sL - sR;
                double gy = dL + 2.0 * d + dR;
                mag += sqrt(gx * gx + gy * gy);
                sgx += gx; sgy += gy;
            }
            if (lane_out) {
                size_t o = (size_t)b * HW + (size_t)ri * WW + cl;
                GM[o] = (float)mag;
                double ax = fabs(sgx), ay = fabs(sgy);
                int kp;
                if (ay <= ax * t225)      kp = (sgx >= 0.0) ? 4 : 0;
                else if (ay >= ax * t675) kp = (sgy > 0.0) ? 6 : 2;
                else if (sgx > 0.0)       kp = (sgy > 0.0) ? 5 : 3;
                else                      kp = (sgy > 0.0) ? 7 : 1;
                KP[o] = (unsigned char)kp;
            }
        }
    };

    float A[3][9], B[3][9];
    LOADROW(R0 - 5, A);
#pragma unroll
    for (int ph = 0; ph < 18; ++ph) {
        if (ph & 1) {
            if (ph < 17) LOADROW(R0 - 4 + ph, A);   // prefetch next row
            COMPUTE(ph, B);
        } else {
            if (ph < 17) LOADROW(R0 - 4 + ph, B);
            COMPUTE(ph, A);
        }
    }
}

// K23 fused: per 32x32 tile, compute the 34x34 halo of CODE bytes into LDS
// (thin/threshold decisions in f64 from f32 GM), then hysteresis.
// code bit0: thin > 0.3 ; bit1: 0.1 <= thin <= 0.3
__global__ __launch_bounds__(256) void canny_thin_out_kernel(
    const float* __restrict__ GM, const unsigned char* __restrict__ KP,
    float* __restrict__ out)
{
    __shared__ unsigned char scode[34 * 35];

    const int tilesX = WW / 32;                 // 16
    const int tx0 = (blockIdx.x % tilesX) * 32;
    const int ty0 = (blockIdx.x / tilesX) * 32;
    const int b = blockIdx.y;
    const int t = threadIdx.x;

    // dr+1 per b (digits b7..b0): 0,0,0,1,2,2,2,1 ; dc+1: 2,1,0,0,0,1,2,2
    const int dr = (int)((0x00012221u >> (b * 4)) & 15u) - 1;
    const int dc = (int)((0x21000122u >> (b * 4)) & 15u) - 1;

    // ---- phase 1: codes for tile+halo (34x34 items, width-34 walk)
    {
        int r = t / 34, cc = t % 34, idx = t;
#pragma unroll
        for (int it = 0; it < 5; ++it) {
            if (idx < 34 * 34) {
                int gi = ty0 - 1 + r, gj = tx0 - 1 + cc;
                unsigned char code = 0;
                if ((unsigned)gi < (unsigned)HH && (unsigned)gj < (unsigned)WW) {
                    size_t p0 = (size_t)gi * WW + gj;
                    int kp = KP[(size_t)b * HW + p0];
                    int kn = (kp + 4) & 7;
                    int ni = gi + dr, nj = gj + dc;
                    bool nin = ((unsigned)ni < (unsigned)HH) && ((unsigned)nj < (unsigned)WW);
                    size_t pn = (size_t)ni * WW + nj;
                    double gmp  = (double)GM[(size_t)kp * HW + p0];
                    double gmn  = (double)GM[(size_t)kn * HW + p0];
                    double gmpn = nin ? (double)GM[(size_t)kp * HW + pn] : 0.0;
                    double gmnn = nin ? (double)GM[(size_t)kn * HW + pn] : 0.0;
                    double pos = gmp - gmpn;
                    double neg = gmn - gmnn;
                    double thin = (fmin(pos, neg) > 0.0) ? (double)GM[(size_t)b * HW + p0] : 0.0;
                    if (thin > 0.3) code |= 1;
                    if (thin >= 0.1 && thin <= 0.3) code |= 2;
                }
                scode[r * 35 + cc] = code;
            }
            idx += 256; r += 7; cc += 18;        // 256 = 7*34 + 18
            if (cc >= 34) { cc -= 34; ++r; }
        }
    }
    __syncthreads();

    // ---- phase 2: hysteresis + border zero, 4 px/thread
#pragma unroll
    for (int p = 0; p < 4; ++p) {
        int pix = t + p * 256;
        int i = pix >> 5, j = pix & 31;
        int gi = ty0 + i, gj = tx0 + j;
        float res = 0.0f;
        if (gi > 0 && gi < HH - 1 && gj > 0 && gj < WW - 1) {
            const unsigned char* sc = scode + (i + 1) * 35 + (j + 1);
            unsigned char c = *sc;
            if (c & 1) {
                res = 1.0f;
            } else if (c & 2) {
                int any = 0;
                any |= sc[-36] & 1; any |= sc[-35] & 1; any |= sc[-34] & 1;
                any |= sc[-1]  & 1; any |= sc[ 1]  & 1;
                any |= sc[ 34] & 1; any |= sc[ 35] & 1; any |= sc[ 36] & 1;
                if (any) res = 1.0f;
            }
        }
        out[(size_t)b * HW + (size_t)gi * WW + gj] = res;
    }
}

extern "C" void kernel_launch(void* const* d_in, const int* in_sizes, int n_in,
                              void* d_out, int out_size, void* d_ws, size_t ws_size,
                              hipStream_t stream) {
    const float* img  = (const float*)d_in[0];
    const float* gwin = (const float*)d_in[1];

    float* GM = (float*)d_ws;                                   // 8 MB
    unsigned char* KP = (unsigned char*)d_ws + (size_t)NB * HW * sizeof(float);
    float* out = (float*)d_out;

    dim3 g1(NCOLS * (NROWS / WPB), NB);   // (144, 8) = 1152 blocks x 256 thr
    canny_gm_kernel<<<g1, 256, 0, stream>>>(img, gwin, GM, KP);

    dim3 g2((WW / 32) * (HH / 32), NB);   // (256, 8) blocks x 256
    canny_thin_out_kernel<<<g2, 256, 0, stream>>>(GM, KP, out);
}

// Round 9
// 107.161 us; speedup vs baseline: 5.4619x; 5.4619x over previous
//
#include <hip/hip_runtime.h>
#include <math.h>

#define HH 512
#define WW 512
#define NB 8
#define NC 3
#define HW (HH*WW)

#define RSTRIP 8                          // output rows per wave
#define CSTRIP 62                         // output cols per wave
#define NROWS (HH/RSTRIP)                 // 64
#define NCOLS ((WW + CSTRIP - 1)/CSTRIP)  // 9
#define WPB 4                             // waves per block

typedef float float4u __attribute__((ext_vector_type(4), aligned(4)));

// ---- macros (textual, all-static indexing -> registers, no scratch) ----

#define LOADROW(RR, V0, V1, V2) do {                                          \
    const int r_ = (RR);                                                      \
    if ((unsigned)r_ < (unsigned)HH) {                                        \
        if (csafe) {                                                          \
            const size_t ro_ = (size_t)r_ * WW + (size_t)(cl - 4);            \
            float4u p_, q_;                                                   \
            p_ = *(const float4u*)(ip0 + ro_);                                \
            q_ = *(const float4u*)(ip0 + ro_ + 4);                            \
            V0[0]=p_[0]; V0[1]=p_[1]; V0[2]=p_[2]; V0[3]=p_[3];               \
            V0[4]=q_[0]; V0[5]=q_[1]; V0[6]=q_[2]; V0[7]=q_[3];               \
            V0[8]=ip0[ro_ + 8];                                               \
            p_ = *(const float4u*)(ip1 + ro_);                                \
            q_ = *(const float4u*)(ip1 + ro_ + 4);                            \
            V1[0]=p_[0]; V1[1]=p_[1]; V1[2]=p_[2]; V1[3]=p_[3];               \
            V1[4]=q_[0]; V1[5]=q_[1]; V1[6]=q_[2]; V1[7]=q_[3];               \
            V1[8]=ip1[ro_ + 8];                                               \
            p_ = *(const float4u*)(ip2 + ro_);                                \
            q_ = *(const float4u*)(ip2 + ro_ + 4);                            \
            V2[0]=p_[0]; V2[1]=p_[1]; V2[2]=p_[2]; V2[3]=p_[3];               \
            V2[4]=q_[0]; V2[5]=q_[1]; V2[6]=q_[2]; V2[7]=q_[3];               \
            V2[8]=ip2[ro_ + 8];                                               \
        } else {                                                              \
            const size_t rw_ = (size_t)r_ * WW;                               \
            _Pragma("unroll")                                                 \
            for (int k = 0; k < 9; ++k) {                                     \
                int cc_ = cl - 4 + k;                                         \
                bool m_ = ((unsigned)cc_ < (unsigned)WW);                     \
                int ci_ = cc_ < 0 ? 0 : (cc_ > WW - 1 ? WW - 1 : cc_);        \
                V0[k] = m_ ? ip0[rw_ + ci_] : 0.0f;                           \
                V1[k] = m_ ? ip1[rw_ + ci_] : 0.0f;                           \
                V2[k] = m_ ? ip2[rw_ + ci_] : 0.0f;                           \
            }                                                                 \
        }                                                                     \
    } else {                                                                  \
        _Pragma("unroll")                                                     \
        for (int k = 0; k < 9; ++k) { V0[k]=0.0f; V1[k]=0.0f; V2[k]=0.0f; }   \
    }                                                                         \
} while (0)

#define SOB1(VR, PH) {                                                        \
    double top_ = up_ ? VR[((PH) - 2) % 3] : 0.0;                             \
    double mid_ =       VR[((PH) - 1) % 3];                                   \
    double bot_ = dn_ ? VR[(PH) % 3]       : 0.0;                             \
    double s_ = top_ + 2.0 * mid_ + bot_;                                     \
    double d_ = top_ - bot_;                                                  \
    double sL_ = __shfl_up(s_, 1), sR_ = __shfl_down(s_, 1);                  \
    double dL_ = __shfl_up(d_, 1), dR_ = __shfl_down(d_, 1);                  \
    sL_ = cml ? sL_ : 0.0;  sR_ = cmr ? sR_ : 0.0;                            \
    dL_ = cml ? dL_ : 0.0;  dR_ = cmr ? dR_ : 0.0;                            \
    double gx_ = sL_ - sR_;                                                   \
    double gy_ = dL_ + 2.0 * d_ + dR_;                                        \
    mag_ += sqrt(gx_ * gx_ + gy_ * gy_);                                      \
    sgx_ += gx_; sgy_ += gy_; }

#define COMPUTE(PH, V0, V1, V2) do {                                          \
    { double a0_ = 0.0, a1_ = 0.0, a2_ = 0.0;                                 \
      _Pragma("unroll")                                                       \
      for (int k = 0; k < 9; ++k) {                                           \
          a0_ = fma(g[k], (double)V0[k], a0_);                                \
          a1_ = fma(g[k], (double)V1[k], a1_);                                \
          a2_ = fma(g[k], (double)V2[k], a2_);                                \
      }                                                                       \
      hb0[(PH) % 9] = a0_; hb1[(PH) % 9] = a1_; hb2[(PH) % 9] = a2_; }        \
    if ((PH) >= 8) {                                                          \
        double c0_ = 0.0, c1_ = 0.0, c2_ = 0.0;                               \
        _Pragma("unroll")                                                     \
        for (int k = 0; k < 9; ++k) {                                         \
            c0_ = fma(g[k], hb0[((PH) + 1 + k) % 9], c0_);                    \
            c1_ = fma(g[k], hb1[((PH) + 1 + k) % 9], c1_);                    \
            c2_ = fma(g[k], hb2[((PH) + 1 + k) % 9], c2_);                    \
        }                                                                     \
        vr0[(PH) % 3] = c0_; vr1[(PH) % 3] = c1_; vr2[(PH) % 3] = c2_; }      \
    if ((PH) >= 10) {                                                         \
        const int ri_ = R0 - 10 + (PH);                                       \
        const bool up_ = (ri_ >= 1), dn_ = (ri_ <= HH - 2);                   \
        double mag_ = 0.0, sgx_ = 0.0, sgy_ = 0.0;                            \
        SOB1(vr0, PH) SOB1(vr1, PH) SOB1(vr2, PH)                             \
        if (lane_out) {                                                       \
            size_t o_ = (size_t)b * HW + (size_t)ri_ * WW + cl;               \
            GM[o_] = (float)mag_;                                             \
            double ax_ = fabs(sgx_), ay_ = fabs(sgy_);                        \
            int kp_;                                                          \
            if (ay_ <= ax_ * t225)      kp_ = (sgx_ >= 0.0) ? 4 : 0;          \
            else if (ay_ >= ax_ * t675) kp_ = (sgy_ > 0.0) ? 6 : 2;           \
            else if (sgx_ > 0.0)        kp_ = (sgy_ > 0.0) ? 5 : 3;           \
            else                        kp_ = (sgy_ > 0.0) ? 7 : 1;           \
            KP[o_] = (unsigned char)kp_;                                      \
        } }                                                                   \
} while (0)

// K1: register row-streaming separable conv; one wave per 62x8 strip, 4 waves
// per block. Double-buffered prefetch: row r+1's 9 VMEM loads issue before row
// r's f64 H/V/sobel compute. Ring schedule identical to r8 (absmax-0 proven).
__global__ __launch_bounds__(256) void canny_gm_kernel(
    const float* __restrict__ img, const float* __restrict__ gwin,
    float* __restrict__ GM, unsigned char* __restrict__ KP)
{
    const int lane = threadIdx.x & 63;
    const int wv   = threadIdx.x >> 6;         // 0..3
    const int cs   = blockIdx.x % NCOLS;
    const int rs   = (blockIdx.x / NCOLS) * WPB + wv;
    const int b    = blockIdx.y;

    const int R0 = rs * RSTRIP;
    const int cl = cs * CSTRIP - 1 + lane;     // this lane's blur column

    double g[9];
#pragma unroll
    for (int k = 0; k < 9; ++k) g[k] = (double)gwin[k];

    const bool csafe = (cs >= 1) && (cs <= NCOLS - 2);
    const bool lane_out = (lane >= 1) && (lane <= CSTRIP) && (cl < WW);
    const bool cml = ((unsigned)(cl - 1) < (unsigned)WW);
    const bool cmr = ((unsigned)(cl + 1) < (unsigned)WW);

    const float* ip0 = img + ((size_t)b * NC + 0) * HW;
    const float* ip1 = img + ((size_t)b * NC + 1) * HW;
    const float* ip2 = img + ((size_t)b * NC + 2) * HW;

    double hb0[9], hb1[9], hb2[9];   // h-blur ring: row R0-5+ph -> slot ph%9
    double vr0[3], vr1[3], vr2[3];   // v-blur ring: row R0-9+ph -> slot ph%3
#pragma unroll
    for (int k = 0; k < 9; ++k) { hb0[k] = 0.0; hb1[k] = 0.0; hb2[k] = 0.0; }
#pragma unroll
    for (int k = 0; k < 3; ++k) { vr0[k] = 0.0; vr1[k] = 0.0; vr2[k] = 0.0; }

    const double t225 = 0.41421356237309503;   // tan(22.5 deg)
    const double t675 = 2.414213562373095;     // tan(67.5 deg)

    float A0[9], A1[9], A2[9], B0[9], B1[9], B2[9];

    LOADROW(R0 - 5, A0, A1, A2);
    LOADROW(R0 - 4, B0, B1, B2);  COMPUTE(0,  A0, A1, A2);
    LOADROW(R0 - 3, A0, A1, A2);  COMPUTE(1,  B0, B1, B2);
    LOADROW(R0 - 2, B0, B1, B2);  COMPUTE(2,  A0, A1, A2);
    LOADROW(R0 - 1, A0, A1, A2);  COMPUTE(3,  B0, B1, B2);
    LOADROW(R0 + 0, B0, B1, B2);  COMPUTE(4,  A0, A1, A2);
    LOADROW(R0 + 1, A0, A1, A2);  COMPUTE(5,  B0, B1, B2);
    LOADROW(R0 + 2, B0, B1, B2);  COMPUTE(6,  A0, A1, A2);
    LOADROW(R0 + 3, A0, A1, A2);  COMPUTE(7,  B0, B1, B2);
    LOADROW(R0 + 4, B0, B1, B2);  COMPUTE(8,  A0, A1, A2);
    LOADROW(R0 + 5, A0, A1, A2);  COMPUTE(9,  B0, B1, B2);
    LOADROW(R0 + 6, B0, B1, B2);  COMPUTE(10, A0, A1, A2);
    LOADROW(R0 + 7, A0, A1, A2);  COMPUTE(11, B0, B1, B2);
    LOADROW(R0 + 8, B0, B1, B2);  COMPUTE(12, A0, A1, A2);
    LOADROW(R0 + 9, A0, A1, A2);  COMPUTE(13, B0, B1, B2);
    LOADROW(R0 +10, B0, B1, B2);  COMPUTE(14, A0, A1, A2);
    LOADROW(R0 +11, A0, A1, A2);  COMPUTE(15, B0, B1, B2);
    LOADROW(R0 +12, B0, B1, B2);  COMPUTE(16, A0, A1, A2);
                                  COMPUTE(17, B0, B1, B2);
}

// K23 fused: per 32x32 tile, compute the 34x34 halo of CODE bytes into LDS
// (thin/threshold decisions in f64 from f32 GM), then hysteresis.
// code bit0: thin > 0.3 ; bit1: 0.1 <= thin <= 0.3
__global__ __launch_bounds__(256) void canny_thin_out_kernel(
    const float* __restrict__ GM, const unsigned char* __restrict__ KP,
    float* __restrict__ out)
{
    __shared__ unsigned char scode[34 * 35];

    const int tilesX = WW / 32;                 // 16
    const int tx0 = (blockIdx.x % tilesX) * 32;
    const int ty0 = (blockIdx.x / tilesX) * 32;
    const int b = blockIdx.y;
    const int t = threadIdx.x;

    // dr+1 per b (digits b7..b0): 0,0,0,1,2,2,2,1 ; dc+1: 2,1,0,0,0,1,2,2
    const int dr = (int)((0x00012221u >> (b * 4)) & 15u) - 1;
    const int dc = (int)((0x21000122u >> (b * 4)) & 15u) - 1;

    // ---- phase 1: codes for tile+halo (34x34 items, width-34 walk)
    {
        int r = t / 34, cc = t % 34, idx = t;
#pragma unroll
        for (int it = 0; it < 5; ++it) {
            if (idx < 34 * 34) {
                int gi = ty0 - 1 + r, gj = tx0 - 1 + cc;
                unsigned char code = 0;
                if ((unsigned)gi < (unsigned)HH && (unsigned)gj < (unsigned)WW) {
                    size_t p0 = (size_t)gi * WW + gj;
                    int kp = KP[(size_t)b * HW + p0];
                    int kn = (kp + 4) & 7;
                    int ni = gi + dr, nj = gj + dc;
                    bool nin = ((unsigned)ni < (unsigned)HH) && ((unsigned)nj < (unsigned)WW);
                    size_t pn = (size_t)ni * WW + nj;
                    double gmp  = (double)GM[(size_t)kp * HW + p0];
                    double gmn  = (double)GM[(size_t)kn * HW + p0];
                    double gmpn = nin ? (double)GM[(size_t)kp * HW + pn] : 0.0;
                    double gmnn = nin ? (double)GM[(size_t)kn * HW + pn] : 0.0;
                    double pos = gmp - gmpn;
                    double neg = gmn - gmnn;
                    double thin = (fmin(pos, neg) > 0.0) ? (double)GM[(size_t)b * HW + p0] : 0.0;
                    if (thin > 0.3) code |= 1;
                    if (thin >= 0.1 && thin <= 0.3) code |= 2;
                }
                scode[r * 35 + cc] = code;
            }
            idx += 256; r += 7; cc += 18;        // 256 = 7*34 + 18
            if (cc >= 34) { cc -= 34; ++r; }
        }
    }
    __syncthreads();

    // ---- phase 2: hysteresis + border zero, 4 px/thread
#pragma unroll
    for (int p = 0; p < 4; ++p) {
        int pix = t + p * 256;
        int i = pix >> 5, j = pix & 31;
        int gi = ty0 + i, gj = tx0 + j;
        float res = 0.0f;
        if (gi > 0 && gi < HH - 1 && gj > 0 && gj < WW - 1) {
            const unsigned char* sc = scode + (i + 1) * 35 + (j + 1);
            unsigned char c = *sc;
            if (c & 1) {
                res = 1.0f;
            } else if (c & 2) {
                int any = 0;
                any |= sc[-36] & 1; any |= sc[-35] & 1; any |= sc[-34] & 1;
                any |= sc[-1]  & 1; any |= sc[ 1]  & 1;
                any |= sc[ 34] & 1; any |= sc[ 35] & 1; any |= sc[ 36] & 1;
                if (any) res = 1.0f;
            }
        }
        out[(size_t)b * HW + (size_t)gi * WW + gj] = res;
    }
}

extern "C" void kernel_launch(void* const* d_in, const int* in_sizes, int n_in,
                              void* d_out, int out_size, void* d_ws, size_t ws_size,
                              hipStream_t stream) {
    const float* img  = (const float*)d_in[0];
    const float* gwin = (const float*)d_in[1];

    float* GM = (float*)d_ws;                                   // 8 MB
    unsigned char* KP = (unsigned char*)d_ws + (size_t)NB * HW * sizeof(float);
    float* out = (float*)d_out;

    dim3 g1(NCOLS * (NROWS / WPB), NB);   // (144, 8) = 1152 blocks x 256 thr
    canny_gm_kernel<<<g1, 256, 0, stream>>>(img, gwin, GM, KP);

    dim3 g2((WW / 32) * (HH / 32), NB);   // (256, 8) blocks x 256
    canny_thin_out_kernel<<<g2, 256, 0, stream>>>(GM, KP, out);
}